// Round 1
// baseline (5510.744 us; speedup 1.0000x reference)
//
#include <hip/hip_runtime.h>
#include <hip/hip_bf16.h>
#include <math.h>

#define T_    2048
#define HID_  1024
#define NH_   16
#define NKV_  4
#define HD_   64
#define E_    8
#define TOPK_ 2
#define INTER_ 3584
#define EPS_  1e-6f

// ---------------- RMSNorm: one block (256 thr) per row ----------------
__global__ __launch_bounds__(256) void rmsnorm_kernel(const float* __restrict__ x,
                                                      const float* __restrict__ w,
                                                      float* __restrict__ o) {
    int t = blockIdx.x;
    const float* xr = x + (size_t)t * HID_;
    float s = 0.f;
    for (int d = threadIdx.x; d < HID_; d += 256) { float v = xr[d]; s += v * v; }
    __shared__ float red[256];
    red[threadIdx.x] = s; __syncthreads();
    for (int off = 128; off > 0; off >>= 1) {
        if (threadIdx.x < off) red[threadIdx.x] += red[threadIdx.x + off];
        __syncthreads();
    }
    float inv = rsqrtf(red[0] / (float)HID_ + EPS_);
    for (int d = threadIdx.x; d < HID_; d += 256)
        o[(size_t)t * HID_ + d] = w[d] * xr[d] * inv;
}

// ---------------- Generic fp32 GEMM: C[M,N] = A[M,K] @ B[N,K]^T (+add) ----------------
__global__ __launch_bounds__(256) void gemm_f32(const float* __restrict__ A,
                                                const float* __restrict__ B,
                                                float* __restrict__ C,
                                                const float* __restrict__ addsrc,
                                                int M, int N, int K) {
    __shared__ float As[16][65];
    __shared__ float Bs[16][65];
    int tid = threadIdx.x;
    int tx = tid & 15, ty = tid >> 4;
    int bm = blockIdx.y * 64, bn = blockIdx.x * 64;
    float acc[4][4];
#pragma unroll
    for (int i = 0; i < 4; i++)
#pragma unroll
        for (int j = 0; j < 4; j++) acc[i][j] = 0.f;

    int mL[4], kL[4];
#pragma unroll
    for (int l = 0; l < 4; l++) { int idx = tid + l * 256; mL[l] = idx >> 4; kL[l] = idx & 15; }

    for (int k0 = 0; k0 < K; k0 += 16) {
#pragma unroll
        for (int l = 0; l < 4; l++) {
            int m = mL[l], kk = kL[l];
            int gr = bm + m;
            As[kk][m] = (gr < M) ? A[(size_t)gr * K + k0 + kk] : 0.f;
            int gc = bn + m;
            Bs[kk][m] = (gc < N) ? B[(size_t)gc * K + k0 + kk] : 0.f;
        }
        __syncthreads();
#pragma unroll
        for (int kk = 0; kk < 16; kk++) {
            float a[4], b[4];
#pragma unroll
            for (int i = 0; i < 4; i++) a[i] = As[kk][ty * 4 + i];
#pragma unroll
            for (int j = 0; j < 4; j++) b[j] = Bs[kk][tx * 4 + j];
#pragma unroll
            for (int i = 0; i < 4; i++)
#pragma unroll
                for (int j = 0; j < 4; j++) acc[i][j] += a[i] * b[j];
        }
        __syncthreads();
    }
#pragma unroll
    for (int i = 0; i < 4; i++) {
        int r = bm + ty * 4 + i;
        if (r >= M) continue;
#pragma unroll
        for (int j = 0; j < 4; j++) {
            int c = bn + tx * 4 + j;
            if (c >= N) continue;
            float v = acc[i][j];
            if (addsrc) v += addsrc[(size_t)r * N + c];
            C[(size_t)r * N + c] = v;
        }
    }
}

// ---------------- RoPE in-place on q and k ----------------
__global__ void rope_kernel(float* __restrict__ qb, float* __restrict__ kb,
                            const int* __restrict__ pos_ids) {
    int idx = blockIdx.x * blockDim.x + threadIdx.x;
    const int totq = T_ * NH_ * 32;
    const int totk = T_ * NKV_ * 32;
    if (idx >= totq + totk) return;
    float* buf; int t, hh, i, hw;
    if (idx < totq) { buf = qb; hw = NH_;  t = idx / (NH_ * 32); int r = idx % (NH_ * 32); hh = r / 32; i = r % 32; }
    else { idx -= totq; buf = kb; hw = NKV_; t = idx / (NKV_ * 32); int r = idx % (NKV_ * 32); hh = r / 32; i = r % 32; }
    float pos = (float)pos_ids[t];
    // inv_freq = theta^(-i/32), theta=1e6 ; ln(1e6)=13.815510558
    float inv = expf(-(float)i * (13.815510558f / 32.0f));
    float fr = pos * inv;
    float c = cosf(fr), s = sinf(fr);
    size_t base = (size_t)t * hw * 64 + (size_t)hh * 64;
    float x1 = buf[base + i], x2 = buf[base + i + 32];
    buf[base + i]      = x1 * c - x2 * s;
    buf[base + i + 32] = x2 * c + x1 * s;
}

// ---------------- Attention: one wave per (t, h), online softmax ----------------
__global__ __launch_bounds__(64) void attn_kernel(const float* __restrict__ qb,
                                                  const float* __restrict__ kb,
                                                  const float* __restrict__ vb,
                                                  float* __restrict__ ob) {
    int t = blockIdx.x, h = blockIdx.y, lane = threadIdx.x;
    int kvh = h >> 2;  // NH/NKV = 4
    float qv = qb[(size_t)t * (NH_ * HD_) + h * HD_ + lane];
    float m = -INFINITY, l = 0.f, acc = 0.f;
    for (int s = 0; s <= t; ++s) {
        float kv = kb[(size_t)s * (NKV_ * HD_) + kvh * HD_ + lane];
        float p = qv * kv;
#pragma unroll
        for (int off = 32; off > 0; off >>= 1) p += __shfl_xor(p, off);
        float score = p * 0.125f;  // 1/sqrt(64)
        float mn = fmaxf(m, score);
        float scale = __expf(m - mn);
        float pe = __expf(score - mn);
        l = l * scale + pe;
        acc = acc * scale + pe * vb[(size_t)s * (NKV_ * HD_) + kvh * HD_ + lane];
        m = mn;
    }
    ob[(size_t)t * (NH_ * HD_) + h * HD_ + lane] = acc / l;
}

// ---------------- Gating: one wave per token ----------------
__global__ __launch_bounds__(64) void gating_kernel(const float* __restrict__ xn2,
                                                    const float* __restrict__ gate_w,
                                                    int* __restrict__ sel,
                                                    float* __restrict__ wt,
                                                    int* __restrict__ counts) {
    int t = blockIdx.x, lane = threadIdx.x;
    const float* x = xn2 + (size_t)t * HID_;
    float logits[E_];
    for (int e = 0; e < E_; e++) {
        float p = 0.f;
        for (int d = lane; d < HID_; d += 64) p += x[d] * gate_w[(size_t)e * HID_ + d];
#pragma unroll
        for (int off = 32; off > 0; off >>= 1) p += __shfl_xor(p, off);
        logits[e] = p;
    }
    float mx = logits[0];
    for (int e = 1; e < E_; e++) mx = fmaxf(mx, logits[e]);
    float pr[E_]; float sum = 0.f;
    for (int e = 0; e < E_; e++) { pr[e] = __expf(logits[e] - mx); sum += pr[e]; }
    // top-2 on probs (monotone with logits); ties keep earlier index (strict >)
    int e1 = 0; float p1 = pr[0];
    for (int e = 1; e < E_; e++) if (pr[e] > p1) { p1 = pr[e]; e1 = e; }
    int e2 = -1; float p2 = -1.f;
    for (int e = 0; e < E_; e++) if (e != e1 && pr[e] > p2) { p2 = pr[e]; e2 = e; }
    if (lane == 0) {
        float denom = p1 + p2;
        sel[t * 2] = e1; sel[t * 2 + 1] = e2;
        wt[t * 2] = p1 / denom; wt[t * 2 + 1] = p2 / denom;
        atomicAdd(&counts[e1], 1);
        atomicAdd(&counts[e2], 1);
    }
}

__global__ void init_counts_kernel(int* counts) {
    if (threadIdx.x < E_) counts[threadIdx.x] = 0;
}

__global__ void prefix_kernel(const int* __restrict__ counts, int* __restrict__ ebase,
                              int* __restrict__ cursor) {
    if (threadIdx.x == 0) {
        int b = 0;
        for (int e = 0; e < E_; e++) { ebase[e] = b; cursor[e] = b; b += counts[e]; }
    }
}

__global__ void scatter_kernel(const int* __restrict__ sel, const float* __restrict__ wt,
                               int* __restrict__ cursor, int* __restrict__ tok_list,
                               float* __restrict__ wt_list) {
    int t = blockIdx.x * blockDim.x + threadIdx.x;
    if (t >= T_) return;
    for (int j = 0; j < 2; j++) {
        int e = sel[t * 2 + j];
        float w = wt[t * 2 + j];
        int p = atomicAdd(&cursor[e], 1);
        tok_list[p] = t;
        wt_list[p] = w;
    }
}

// ---------------- MoE GEMM 1&3 fused: h13 = silu(Xg@w1^T) * (Xg@w3^T) ----------------
__global__ __launch_bounds__(256) void moe_gemm13(const float* __restrict__ X,
                                                  const float* __restrict__ w1,
                                                  const float* __restrict__ w3,
                                                  const int* __restrict__ tok_list,
                                                  const int* __restrict__ ebase,
                                                  const int* __restrict__ counts,
                                                  float* __restrict__ h13) {
    int e = blockIdx.z;
    int cnt = counts[e];
    int bm = blockIdx.y * 64;
    if (bm >= cnt) return;
    int base = ebase[e];
    const float* B1 = w1 + (size_t)e * INTER_ * HID_;
    const float* B3 = w3 + (size_t)e * INTER_ * HID_;
    __shared__ float As[16][65];
    __shared__ float Bs1[16][65];
    __shared__ float Bs3[16][65];
    int tid = threadIdx.x;
    int tx = tid & 15, ty = tid >> 4;
    int bn = blockIdx.x * 64;
    float acc1[4][4], acc3[4][4];
#pragma unroll
    for (int i = 0; i < 4; i++)
#pragma unroll
        for (int j = 0; j < 4; j++) { acc1[i][j] = 0.f; acc3[i][j] = 0.f; }

    int rowA[4], mL[4], kL[4];
#pragma unroll
    for (int l = 0; l < 4; l++) {
        int idx = tid + l * 256; int m = idx >> 4;
        mL[l] = m; kL[l] = idx & 15;
        int lr = bm + m;
        rowA[l] = (lr < cnt) ? tok_list[base + lr] : -1;
    }
    for (int k0 = 0; k0 < HID_; k0 += 16) {
#pragma unroll
        for (int l = 0; l < 4; l++) {
            int m = mL[l], kk = kL[l];
            As[kk][m] = (rowA[l] >= 0) ? X[(size_t)rowA[l] * HID_ + k0 + kk] : 0.f;
            int gc = bn + m;
            Bs1[kk][m] = B1[(size_t)gc * HID_ + k0 + kk];
            Bs3[kk][m] = B3[(size_t)gc * HID_ + k0 + kk];
        }
        __syncthreads();
#pragma unroll
        for (int kk = 0; kk < 16; kk++) {
            float a[4], b1[4], b3[4];
#pragma unroll
            for (int i = 0; i < 4; i++) a[i] = As[kk][ty * 4 + i];
#pragma unroll
            for (int j = 0; j < 4; j++) { b1[j] = Bs1[kk][tx * 4 + j]; b3[j] = Bs3[kk][tx * 4 + j]; }
#pragma unroll
            for (int i = 0; i < 4; i++)
#pragma unroll
                for (int j = 0; j < 4; j++) { acc1[i][j] += a[i] * b1[j]; acc3[i][j] += a[i] * b3[j]; }
        }
        __syncthreads();
    }
#pragma unroll
    for (int i = 0; i < 4; i++) {
        int lr = bm + ty * 4 + i;
        if (lr >= cnt) continue;
#pragma unroll
        for (int j = 0; j < 4; j++) {
            int c = bn + tx * 4 + j;
            float a = acc1[i][j];
            float sl = a / (1.f + __expf(-a));   // silu
            h13[(size_t)(base + lr) * INTER_ + c] = sl * acc3[i][j];
        }
    }
}

// ---------------- MoE GEMM 2: out[tok] += wt * (h13 @ w2^T) ----------------
__global__ __launch_bounds__(256) void moe_gemm2(const float* __restrict__ h13,
                                                 const float* __restrict__ w2,
                                                 const int* __restrict__ tok_list,
                                                 const float* __restrict__ wt_list,
                                                 const int* __restrict__ ebase,
                                                 const int* __restrict__ counts,
                                                 float* __restrict__ out) {
    int e = blockIdx.z;
    int cnt = counts[e];
    int bm = blockIdx.y * 64;
    if (bm >= cnt) return;
    int base = ebase[e];
    const float* A = h13 + (size_t)base * INTER_;
    const float* B = w2 + (size_t)e * HID_ * INTER_;
    __shared__ float As[16][65];
    __shared__ float Bs[16][65];
    int tid = threadIdx.x;
    int tx = tid & 15, ty = tid >> 4;
    int bn = blockIdx.x * 64;
    float acc[4][4];
#pragma unroll
    for (int i = 0; i < 4; i++)
#pragma unroll
        for (int j = 0; j < 4; j++) acc[i][j] = 0.f;

    int mL[4], kL[4];
#pragma unroll
    for (int l = 0; l < 4; l++) { int idx = tid + l * 256; mL[l] = idx >> 4; kL[l] = idx & 15; }

    for (int k0 = 0; k0 < INTER_; k0 += 16) {
#pragma unroll
        for (int l = 0; l < 4; l++) {
            int m = mL[l], kk = kL[l];
            int lr = bm + m;
            As[kk][m] = (lr < cnt) ? A[(size_t)lr * INTER_ + k0 + kk] : 0.f;
            int gc = bn + m;
            Bs[kk][m] = B[(size_t)gc * INTER_ + k0 + kk];
        }
        __syncthreads();
#pragma unroll
        for (int kk = 0; kk < 16; kk++) {
            float a[4], b[4];
#pragma unroll
            for (int i = 0; i < 4; i++) a[i] = As[kk][ty * 4 + i];
#pragma unroll
            for (int j = 0; j < 4; j++) b[j] = Bs[kk][tx * 4 + j];
#pragma unroll
            for (int i = 0; i < 4; i++)
#pragma unroll
                for (int j = 0; j < 4; j++) acc[i][j] += a[i] * b[j];
        }
        __syncthreads();
    }
#pragma unroll
    for (int i = 0; i < 4; i++) {
        int lr = bm + ty * 4 + i;
        if (lr >= cnt) continue;
        int tok = tok_list[base + lr];
        float w = wt_list[base + lr];
#pragma unroll
        for (int j = 0; j < 4; j++) {
            int c = bn + tx * 4 + j;
            atomicAdd(&out[(size_t)tok * HID_ + c], w * acc[i][j]);
        }
    }
}

__global__ void copy4_kernel(const float* __restrict__ src, float* __restrict__ dst, int n4) {
    int i = blockIdx.x * blockDim.x + threadIdx.x;
    if (i < n4) ((float4*)dst)[i] = ((const float4*)src)[i];
}

extern "C" void kernel_launch(void* const* d_in, const int* in_sizes, int n_in,
                              void* d_out, int out_size, void* d_ws, size_t ws_size,
                              hipStream_t stream) {
    const float* h      = (const float*)d_in[0];
    const int*   pos    = (const int*)d_in[1];
    const float* wq     = (const float*)d_in[2];
    const float* wk     = (const float*)d_in[3];
    const float* wv     = (const float*)d_in[4];
    const float* wo     = (const float*)d_in[5];
    const float* gate_w = (const float*)d_in[6];
    const float* w1     = (const float*)d_in[7];
    const float* w2     = (const float*)d_in[8];
    const float* w3     = (const float*)d_in[9];
    const float* ln1_w  = (const float*)d_in[10];
    const float* ln2_w  = (const float*)d_in[11];
    float* out = (float*)d_out;

    float* ws = (float*)d_ws;
    const size_t M1 = 1024 * 1024;  // 1M floats
    float* xn1 = ws;                 // 2M  (aliased: attention output ob)
    float* ob  = ws;                 // alias of xn1 (xn1 dead after QKV gemms)
    float* qb  = ws + 2 * M1;        // 2M  (aliased: h2 after attention)
    float* h2  = ws + 2 * M1;        // alias of qb
    float* kb  = ws + 4 * M1;        // 0.5M
    float* vb  = ws + 4 * M1 + M1 / 2; // 0.5M
    float* xn2 = ws + 5 * M1;        // 2M
    float* h13 = ws + 7 * M1;        // 2T*INTER = 14,680,064 floats
    float* smallf = ws + 7 * M1 + 15 * M1;  // small region at +22M floats
    int*   sel      = (int*)smallf;              // 4096
    float* wtb      = smallf + 4096;             // 4096
    int*   counts   = (int*)(smallf + 8192);     // 8
    int*   ebase    = (int*)(smallf + 8192 + 16);// 8
    int*   cursor   = (int*)(smallf + 8192 + 32);// 8
    int*   tok_list = (int*)(smallf + 8192 + 64);// 4096
    float* wt_list  = smallf + 8192 + 64 + 4096; // 4096

    // 1. init counts
    hipLaunchKernelGGL(init_counts_kernel, dim3(1), dim3(64), 0, stream, counts);
    // 2. rmsnorm(h) -> xn1
    hipLaunchKernelGGL(rmsnorm_kernel, dim3(T_), dim3(256), 0, stream, h, ln1_w, xn1);
    // 3-5. QKV projections
    hipLaunchKernelGGL(gemm_f32, dim3(16, 32), dim3(256), 0, stream, xn1, wq, qb, (const float*)nullptr, T_, NH_ * HD_, HID_);
    hipLaunchKernelGGL(gemm_f32, dim3(4, 32),  dim3(256), 0, stream, xn1, wk, kb, (const float*)nullptr, T_, NKV_ * HD_, HID_);
    hipLaunchKernelGGL(gemm_f32, dim3(4, 32),  dim3(256), 0, stream, xn1, wv, vb, (const float*)nullptr, T_, NKV_ * HD_, HID_);
    // 6. RoPE (in-place q, k)
    {
        int tot = T_ * (NH_ + NKV_) * 32;
        hipLaunchKernelGGL(rope_kernel, dim3((tot + 255) / 256), dim3(256), 0, stream, qb, kb, pos);
    }
    // 7. attention -> ob (aliases xn1, which is dead now)
    hipLaunchKernelGGL(attn_kernel, dim3(T_, NH_), dim3(64), 0, stream, qb, kb, vb, ob);
    // 8. wo projection + residual(h) -> h2 (aliases qb, dead after attention)
    hipLaunchKernelGGL(gemm_f32, dim3(16, 32), dim3(256), 0, stream, ob, wo, h2, h, T_, HID_, NH_ * HD_);
    // 9. rmsnorm(h2) -> xn2
    hipLaunchKernelGGL(rmsnorm_kernel, dim3(T_), dim3(256), 0, stream, h2, ln2_w, xn2);
    // 10. gating
    hipLaunchKernelGGL(gating_kernel, dim3(T_), dim3(64), 0, stream, xn2, gate_w, sel, wtb, counts);
    // 11. prefix
    hipLaunchKernelGGL(prefix_kernel, dim3(1), dim3(64), 0, stream, counts, ebase, cursor);
    // 12. scatter
    hipLaunchKernelGGL(scatter_kernel, dim3((T_ + 255) / 256), dim3(256), 0, stream, sel, wtb, cursor, tok_list, wt_list);
    // 13. moe13: h13 = silu(Xg@w1^T)*(Xg@w3^T)
    hipLaunchKernelGGL(moe_gemm13, dim3(INTER_ / 64, T_ / 64, E_), dim3(256), 0, stream,
                       xn2, w1, w3, tok_list, ebase, counts, h13);
    // 14. out = h2
    hipLaunchKernelGGL(copy4_kernel, dim3((T_ * HID_ / 4 + 255) / 256), dim3(256), 0, stream, h2, out, T_ * HID_ / 4);
    // 15. moe2: out += wt * (h13 @ w2^T)
    hipLaunchKernelGGL(moe_gemm2, dim3(HID_ / 64, T_ / 64, E_), dim3(256), 0, stream,
                       h13, w2, tok_list, wt_list, ebase, counts, out);
}

// Round 3
// 3229.763 us; speedup vs baseline: 1.7062x; 1.7062x over previous
//
#include <hip/hip_runtime.h>
#include <hip/hip_bf16.h>
#include <math.h>

#define T_    2048
#define HID_  1024
#define NH_   16
#define NKV_  4
#define HD_   64
#define E_    8
#define TOPK_ 2
#define INTER_ 3584
#define EPS_  1e-6f

// ---------------- RMSNorm: one block (256 thr) per row ----------------
__global__ __launch_bounds__(256) void rmsnorm_kernel(const float* __restrict__ x,
                                                      const float* __restrict__ w,
                                                      float* __restrict__ o) {
    int t = blockIdx.x;
    const float* xr = x + (size_t)t * HID_;
    float s = 0.f;
    for (int d = threadIdx.x; d < HID_; d += 256) { float v = xr[d]; s += v * v; }
    __shared__ float red[256];
    red[threadIdx.x] = s; __syncthreads();
    for (int off = 128; off > 0; off >>= 1) {
        if (threadIdx.x < off) red[threadIdx.x] += red[threadIdx.x + off];
        __syncthreads();
    }
    float inv = rsqrtf(red[0] / (float)HID_ + EPS_);
    for (int d = threadIdx.x; d < HID_; d += 256)
        o[(size_t)t * HID_ + d] = w[d] * xr[d] * inv;
}

// ---------------- Generic fp32 GEMM: C[M,N] = A[M,K] @ B[N,K]^T (+add) ----------------
__global__ __launch_bounds__(256) void gemm_f32(const float* __restrict__ A,
                                                const float* __restrict__ B,
                                                float* __restrict__ C,
                                                const float* __restrict__ addsrc,
                                                int M, int N, int K) {
    __shared__ float As[16][65];
    __shared__ float Bs[16][65];
    int tid = threadIdx.x;
    int tx = tid & 15, ty = tid >> 4;
    int bm = blockIdx.y * 64, bn = blockIdx.x * 64;
    float acc[4][4];
#pragma unroll
    for (int i = 0; i < 4; i++)
#pragma unroll
        for (int j = 0; j < 4; j++) acc[i][j] = 0.f;

    int mL[4], kL[4];
#pragma unroll
    for (int l = 0; l < 4; l++) { int idx = tid + l * 256; mL[l] = idx >> 4; kL[l] = idx & 15; }

    for (int k0 = 0; k0 < K; k0 += 16) {
#pragma unroll
        for (int l = 0; l < 4; l++) {
            int m = mL[l], kk = kL[l];
            int gr = bm + m;
            As[kk][m] = (gr < M) ? A[(size_t)gr * K + k0 + kk] : 0.f;
            int gc = bn + m;
            Bs[kk][m] = (gc < N) ? B[(size_t)gc * K + k0 + kk] : 0.f;
        }
        __syncthreads();
#pragma unroll
        for (int kk = 0; kk < 16; kk++) {
            float a[4], b[4];
#pragma unroll
            for (int i = 0; i < 4; i++) a[i] = As[kk][ty * 4 + i];
#pragma unroll
            for (int j = 0; j < 4; j++) b[j] = Bs[kk][tx * 4 + j];
#pragma unroll
            for (int i = 0; i < 4; i++)
#pragma unroll
                for (int j = 0; j < 4; j++) acc[i][j] += a[i] * b[j];
        }
        __syncthreads();
    }
#pragma unroll
    for (int i = 0; i < 4; i++) {
        int r = bm + ty * 4 + i;
        if (r >= M) continue;
#pragma unroll
        for (int j = 0; j < 4; j++) {
            int c = bn + tx * 4 + j;
            if (c >= N) continue;
            float v = acc[i][j];
            if (addsrc) v += addsrc[(size_t)r * N + c];
            C[(size_t)r * N + c] = v;
        }
    }
}

// ---------------- RoPE in-place on q and k ----------------
__global__ void rope_kernel(float* __restrict__ qb, float* __restrict__ kb,
                            const int* __restrict__ pos_ids) {
    int idx = blockIdx.x * blockDim.x + threadIdx.x;
    const int totq = T_ * NH_ * 32;
    const int totk = T_ * NKV_ * 32;
    if (idx >= totq + totk) return;
    float* buf; int t, hh, i, hw;
    if (idx < totq) { buf = qb; hw = NH_;  t = idx / (NH_ * 32); int r = idx % (NH_ * 32); hh = r / 32; i = r % 32; }
    else { idx -= totq; buf = kb; hw = NKV_; t = idx / (NKV_ * 32); int r = idx % (NKV_ * 32); hh = r / 32; i = r % 32; }
    float pos = (float)pos_ids[t];
    // inv_freq = theta^(-i/32), theta=1e6 ; ln(1e6)=13.815510558
    float inv = expf(-(float)i * (13.815510558f / 32.0f));
    float fr = pos * inv;
    float c = cosf(fr), s = sinf(fr);
    size_t base = (size_t)t * hw * 64 + (size_t)hh * 64;
    float x1 = buf[base + i], x2 = buf[base + i + 32];
    buf[base + i]      = x1 * c - x2 * s;
    buf[base + i + 32] = x2 * c + x1 * s;
}

// ---------------- Flash attention: one block per (head, 64-row q-tile) ----------------
// 256 threads = 16x16; each thread owns a 4x4 micro-tile of the 64x64 score
// tile and a 4x4 micro-tile of the 64-wide output accumulator.
// LDS layouts: Qs[d][seq], Ks[d][seq] (feature-major, for S = Q@K^T);
//              Vs[seq][d] (sequence-major, for O += P@V);  Ps[s][q_row].
__global__ __launch_bounds__(256) void flash_attn_kernel(const float* __restrict__ qb,
                                                         const float* __restrict__ kb,
                                                         const float* __restrict__ vb,
                                                         float* __restrict__ ob) {
    // pad to 68 floats: row stride 272B is 16B-aligned so float4 reads stay aligned
    __shared__ float Qs[64][68];
    __shared__ float Ks[64][68];
    __shared__ float Vs[64][68];
    __shared__ float Ps[64][68];

    int bid = blockIdx.x;
    int h = bid & 15;
    int qr = bid >> 4;                         // 0..31
    int qt = (qr & 1) ? (31 - (qr >> 1)) : (qr >> 1);  // interleave long/short blocks
    int q0 = qt * 64;
    int kvh = h >> 2;
    int tid = threadIdx.x;
    int tx = tid & 15, ty = tid >> 4;

    // load Q tile: Qs[d][m] = q[q0+m][h][d]
#pragma unroll
    for (int l = 0; l < 16; l++) {
        int idx = l * 256 + tid;
        int m = idx >> 6, d = idx & 63;
        Qs[d][m] = qb[(size_t)(q0 + m) * (NH_ * HD_) + h * HD_ + d];
    }

    float o_acc[4][4];
    float m_i[4], l_i[4];
#pragma unroll
    for (int i = 0; i < 4; i++) {
        m_i[i] = -INFINITY; l_i[i] = 0.f;
#pragma unroll
        for (int j = 0; j < 4; j++) o_acc[i][j] = 0.f;
    }

    for (int t0 = 0; t0 <= q0; t0 += 64) {
        __syncthreads();   // prev GEMM2 reads of Ks/Vs/Ps done
        // load K tile feature-major, V tile sequence-major
#pragma unroll
        for (int l = 0; l < 16; l++) {
            int idx = l * 256 + tid;
            int m = idx >> 6, d = idx & 63;
            size_t g = (size_t)(t0 + m) * (NKV_ * HD_) + kvh * HD_ + d;
            Ks[d][m] = kb[g];
            Vs[m][d] = vb[g];
        }
        __syncthreads();

        // GEMM1: S = Q @ K^T over d
        float s[4][4];
#pragma unroll
        for (int i = 0; i < 4; i++)
#pragma unroll
            for (int j = 0; j < 4; j++) s[i][j] = 0.f;
#pragma unroll 4
        for (int kk = 0; kk < 64; kk++) {
            float4 a4 = *(const float4*)&Qs[kk][ty * 4];
            float4 b4 = *(const float4*)&Ks[kk][tx * 4];
            float a[4] = {a4.x, a4.y, a4.z, a4.w};
            float b[4] = {b4.x, b4.y, b4.z, b4.w};
#pragma unroll
            for (int i = 0; i < 4; i++)
#pragma unroll
                for (int j = 0; j < 4; j++) s[i][j] += a[i] * b[j];
        }

        bool diag = (t0 == q0);
#pragma unroll
        for (int i = 0; i < 4; i++) {
#pragma unroll
            for (int j = 0; j < 4; j++) {
                s[i][j] *= 0.125f;   // 1/sqrt(64)
                if (diag && (t0 + tx * 4 + j > q0 + ty * 4 + i)) s[i][j] = -INFINITY;
            }
        }

        // online softmax per row (reduce across the 16 tx lanes of this wave)
#pragma unroll
        for (int i = 0; i < 4; i++) {
            float mx = fmaxf(fmaxf(s[i][0], s[i][1]), fmaxf(s[i][2], s[i][3]));
#pragma unroll
            for (int off = 8; off >= 1; off >>= 1) mx = fmaxf(mx, __shfl_xor(mx, off));
            float mn = fmaxf(m_i[i], mx);
            float alpha = __expf(m_i[i] - mn);
            float rs = 0.f;
#pragma unroll
            for (int j = 0; j < 4; j++) { float p = __expf(s[i][j] - mn); s[i][j] = p; rs += p; }
#pragma unroll
            for (int off = 8; off >= 1; off >>= 1) rs += __shfl_xor(rs, off);
            l_i[i] = l_i[i] * alpha + rs;
            m_i[i] = mn;
#pragma unroll
            for (int j = 0; j < 4; j++) o_acc[i][j] *= alpha;
        }

        // write P transposed: Ps[s_col][q_row]
#pragma unroll
        for (int j = 0; j < 4; j++)
#pragma unroll
            for (int i = 0; i < 4; i++)
                Ps[tx * 4 + j][ty * 4 + i] = s[i][j];
        __syncthreads();

        // GEMM2: O += P @ V over s   (Ps[s][row], Vs[s][d])
#pragma unroll 4
        for (int kk = 0; kk < 64; kk++) {
            float4 a4 = *(const float4*)&Ps[kk][ty * 4];
            float4 b4 = *(const float4*)&Vs[kk][tx * 4];
            float a[4] = {a4.x, a4.y, a4.z, a4.w};
            float b[4] = {b4.x, b4.y, b4.z, b4.w};
#pragma unroll
            for (int i = 0; i < 4; i++)
#pragma unroll
                for (int j = 0; j < 4; j++) o_acc[i][j] += a[i] * b[j];
        }
    }

#pragma unroll
    for (int i = 0; i < 4; i++) {
        float invl = 1.f / l_i[i];
        int r = q0 + ty * 4 + i;
#pragma unroll
        for (int j = 0; j < 4; j++)
            ob[(size_t)r * (NH_ * HD_) + h * HD_ + tx * 4 + j] = o_acc[i][j] * invl;
    }
}

// ---------------- Gating: one wave per token ----------------
__global__ __launch_bounds__(64) void gating_kernel(const float* __restrict__ xn2,
                                                    const float* __restrict__ gate_w,
                                                    int* __restrict__ sel,
                                                    float* __restrict__ wt,
                                                    int* __restrict__ counts) {
    int t = blockIdx.x, lane = threadIdx.x;
    const float* x = xn2 + (size_t)t * HID_;
    float logits[E_];
    for (int e = 0; e < E_; e++) {
        float p = 0.f;
        for (int d = lane; d < HID_; d += 64) p += x[d] * gate_w[(size_t)e * HID_ + d];
#pragma unroll
        for (int off = 32; off > 0; off >>= 1) p += __shfl_xor(p, off);
        logits[e] = p;
    }
    float mx = logits[0];
    for (int e = 1; e < E_; e++) mx = fmaxf(mx, logits[e]);
    float pr[E_]; float sum = 0.f;
    for (int e = 0; e < E_; e++) { pr[e] = __expf(logits[e] - mx); sum += pr[e]; }
    int e1 = 0; float p1 = pr[0];
    for (int e = 1; e < E_; e++) if (pr[e] > p1) { p1 = pr[e]; e1 = e; }
    int e2 = -1; float p2 = -1.f;
    for (int e = 0; e < E_; e++) if (e != e1 && pr[e] > p2) { p2 = pr[e]; e2 = e; }
    if (lane == 0) {
        float denom = p1 + p2;
        sel[t * 2] = e1; sel[t * 2 + 1] = e2;
        wt[t * 2] = p1 / denom; wt[t * 2 + 1] = p2 / denom;
        atomicAdd(&counts[e1], 1);
        atomicAdd(&counts[e2], 1);
    }
}

__global__ void init_counts_kernel(int* counts) {
    if (threadIdx.x < E_) counts[threadIdx.x] = 0;
}

__global__ void prefix_kernel(const int* __restrict__ counts, int* __restrict__ ebase,
                              int* __restrict__ cursor) {
    if (threadIdx.x == 0) {
        int b = 0;
        for (int e = 0; e < E_; e++) { ebase[e] = b; cursor[e] = b; b += counts[e]; }
    }
}

__global__ void scatter_kernel(const int* __restrict__ sel, const float* __restrict__ wt,
                               int* __restrict__ cursor, int* __restrict__ tok_list,
                               float* __restrict__ wt_list) {
    int t = blockIdx.x * blockDim.x + threadIdx.x;
    if (t >= T_) return;
    for (int j = 0; j < 2; j++) {
        int e = sel[t * 2 + j];
        float w = wt[t * 2 + j];
        int p = atomicAdd(&cursor[e], 1);
        tok_list[p] = t;
        wt_list[p] = w;
    }
}

// ---------------- MoE GEMM 1&3 fused: h13 = silu(Xg@w1^T) * (Xg@w3^T) ----------------
__global__ __launch_bounds__(256) void moe_gemm13(const float* __restrict__ X,
                                                  const float* __restrict__ w1,
                                                  const float* __restrict__ w3,
                                                  const int* __restrict__ tok_list,
                                                  const int* __restrict__ ebase,
                                                  const int* __restrict__ counts,
                                                  float* __restrict__ h13) {
    int e = blockIdx.z;
    int cnt = counts[e];
    int bm = blockIdx.y * 64;
    if (bm >= cnt) return;
    int base = ebase[e];
    const float* B1 = w1 + (size_t)e * INTER_ * HID_;
    const float* B3 = w3 + (size_t)e * INTER_ * HID_;
    __shared__ float As[16][65];
    __shared__ float Bs1[16][65];
    __shared__ float Bs3[16][65];
    int tid = threadIdx.x;
    int tx = tid & 15, ty = tid >> 4;
    int bn = blockIdx.x * 64;
    float acc1[4][4], acc3[4][4];
#pragma unroll
    for (int i = 0; i < 4; i++)
#pragma unroll
        for (int j = 0; j < 4; j++) { acc1[i][j] = 0.f; acc3[i][j] = 0.f; }

    int rowA[4], mL[4], kL[4];
#pragma unroll
    for (int l = 0; l < 4; l++) {
        int idx = tid + l * 256; int m = idx >> 4;
        mL[l] = m; kL[l] = idx & 15;
        int lr = bm + m;
        rowA[l] = (lr < cnt) ? tok_list[base + lr] : -1;
    }
    for (int k0 = 0; k0 < HID_; k0 += 16) {
#pragma unroll
        for (int l = 0; l < 4; l++) {
            int m = mL[l], kk = kL[l];
            As[kk][m] = (rowA[l] >= 0) ? X[(size_t)rowA[l] * HID_ + k0 + kk] : 0.f;
            int gc = bn + m;
            Bs1[kk][m] = B1[(size_t)gc * HID_ + k0 + kk];
            Bs3[kk][m] = B3[(size_t)gc * HID_ + k0 + kk];
        }
        __syncthreads();
#pragma unroll
        for (int kk = 0; kk < 16; kk++) {
            float a[4], b1[4], b3[4];
#pragma unroll
            for (int i = 0; i < 4; i++) a[i] = As[kk][ty * 4 + i];
#pragma unroll
            for (int j = 0; j < 4; j++) { b1[j] = Bs1[kk][tx * 4 + j]; b3[j] = Bs3[kk][tx * 4 + j]; }
#pragma unroll
            for (int i = 0; i < 4; i++)
#pragma unroll
                for (int j = 0; j < 4; j++) { acc1[i][j] += a[i] * b1[j]; acc3[i][j] += a[i] * b3[j]; }
        }
        __syncthreads();
    }
#pragma unroll
    for (int i = 0; i < 4; i++) {
        int lr = bm + ty * 4 + i;
        if (lr >= cnt) continue;
#pragma unroll
        for (int j = 0; j < 4; j++) {
            int c = bn + tx * 4 + j;
            float a = acc1[i][j];
            float sl = a / (1.f + __expf(-a));   // silu
            h13[(size_t)(base + lr) * INTER_ + c] = sl * acc3[i][j];
        }
    }
}

// ---------------- MoE GEMM 2: out[tok] += wt * (h13 @ w2^T) ----------------
__global__ __launch_bounds__(256) void moe_gemm2(const float* __restrict__ h13,
                                                 const float* __restrict__ w2,
                                                 const int* __restrict__ tok_list,
                                                 const float* __restrict__ wt_list,
                                                 const int* __restrict__ ebase,
                                                 const int* __restrict__ counts,
                                                 float* __restrict__ out) {
    int e = blockIdx.z;
    int cnt = counts[e];
    int bm = blockIdx.y * 64;
    if (bm >= cnt) return;
    int base = ebase[e];
    const float* A = h13 + (size_t)base * INTER_;
    const float* B = w2 + (size_t)e * HID_ * INTER_;
    __shared__ float As[16][65];
    __shared__ float Bs[16][65];
    int tid = threadIdx.x;
    int tx = tid & 15, ty = tid >> 4;
    int bn = blockIdx.x * 64;
    float acc[4][4];
#pragma unroll
    for (int i = 0; i < 4; i++)
#pragma unroll
        for (int j = 0; j < 4; j++) acc[i][j] = 0.f;

    int mL[4], kL[4];
#pragma unroll
    for (int l = 0; l < 4; l++) { int idx = tid + l * 256; mL[l] = idx >> 4; kL[l] = idx & 15; }

    for (int k0 = 0; k0 < INTER_; k0 += 16) {
#pragma unroll
        for (int l = 0; l < 4; l++) {
            int m = mL[l], kk = kL[l];
            int lr = bm + m;
            As[kk][m] = (lr < cnt) ? A[(size_t)lr * INTER_ + k0 + kk] : 0.f;
            int gc = bn + m;
            Bs[kk][m] = B[(size_t)gc * INTER_ + k0 + kk];
        }
        __syncthreads();
#pragma unroll
        for (int kk = 0; kk < 16; kk++) {
            float a[4], b[4];
#pragma unroll
            for (int i = 0; i < 4; i++) a[i] = As[kk][ty * 4 + i];
#pragma unroll
            for (int j = 0; j < 4; j++) b[j] = Bs[kk][tx * 4 + j];
#pragma unroll
            for (int i = 0; i < 4; i++)
#pragma unroll
                for (int j = 0; j < 4; j++) acc[i][j] += a[i] * b[j];
        }
        __syncthreads();
    }
#pragma unroll
    for (int i = 0; i < 4; i++) {
        int lr = bm + ty * 4 + i;
        if (lr >= cnt) continue;
        int tok = tok_list[base + lr];
        float w = wt_list[base + lr];
#pragma unroll
        for (int j = 0; j < 4; j++) {
            int c = bn + tx * 4 + j;
            atomicAdd(&out[(size_t)tok * HID_ + c], w * acc[i][j]);
        }
    }
}

__global__ void copy4_kernel(const float* __restrict__ src, float* __restrict__ dst, int n4) {
    int i = blockIdx.x * blockDim.x + threadIdx.x;
    if (i < n4) ((float4*)dst)[i] = ((const float4*)src)[i];
}

extern "C" void kernel_launch(void* const* d_in, const int* in_sizes, int n_in,
                              void* d_out, int out_size, void* d_ws, size_t ws_size,
                              hipStream_t stream) {
    const float* h      = (const float*)d_in[0];
    const int*   pos    = (const int*)d_in[1];
    const float* wq     = (const float*)d_in[2];
    const float* wk     = (const float*)d_in[3];
    const float* wv     = (const float*)d_in[4];
    const float* wo     = (const float*)d_in[5];
    const float* gate_w = (const float*)d_in[6];
    const float* w1     = (const float*)d_in[7];
    const float* w2     = (const float*)d_in[8];
    const float* w3     = (const float*)d_in[9];
    const float* ln1_w  = (const float*)d_in[10];
    const float* ln2_w  = (const float*)d_in[11];
    float* out = (float*)d_out;

    float* ws = (float*)d_ws;
    const size_t M1 = 1024 * 1024;  // 1M floats
    float* xn1 = ws;                 // 2M  (aliased: attention output ob)
    float* ob  = ws;                 // alias of xn1 (xn1 dead after QKV gemms)
    float* qb  = ws + 2 * M1;        // 2M  (aliased: h2 after attention)
    float* h2  = ws + 2 * M1;        // alias of qb
    float* kb  = ws + 4 * M1;        // 0.5M
    float* vb  = ws + 4 * M1 + M1 / 2; // 0.5M
    float* xn2 = ws + 5 * M1;        // 2M
    float* h13 = ws + 7 * M1;        // 2T*INTER = 14,680,064 floats
    float* smallf = ws + 7 * M1 + 15 * M1;  // small region at +22M floats
    int*   sel      = (int*)smallf;              // 4096
    float* wtb      = smallf + 4096;             // 4096
    int*   counts   = (int*)(smallf + 8192);     // 8
    int*   ebase    = (int*)(smallf + 8192 + 16);// 8
    int*   cursor   = (int*)(smallf + 8192 + 32);// 8
    int*   tok_list = (int*)(smallf + 8192 + 64);// 4096
    float* wt_list  = smallf + 8192 + 64 + 4096; // 4096

    // 1. init counts
    hipLaunchKernelGGL(init_counts_kernel, dim3(1), dim3(64), 0, stream, counts);
    // 2. rmsnorm(h) -> xn1
    hipLaunchKernelGGL(rmsnorm_kernel, dim3(T_), dim3(256), 0, stream, h, ln1_w, xn1);
    // 3-5. QKV projections
    hipLaunchKernelGGL(gemm_f32, dim3(16, 32), dim3(256), 0, stream, xn1, wq, qb, (const float*)nullptr, T_, NH_ * HD_, HID_);
    hipLaunchKernelGGL(gemm_f32, dim3(4, 32),  dim3(256), 0, stream, xn1, wk, kb, (const float*)nullptr, T_, NKV_ * HD_, HID_);
    hipLaunchKernelGGL(gemm_f32, dim3(4, 32),  dim3(256), 0, stream, xn1, wv, vb, (const float*)nullptr, T_, NKV_ * HD_, HID_);
    // 6. RoPE (in-place q, k)
    {
        int tot = T_ * (NH_ + NKV_) * 32;
        hipLaunchKernelGGL(rope_kernel, dim3((tot + 255) / 256), dim3(256), 0, stream, qb, kb, pos);
    }
    // 7. flash attention -> ob (aliases xn1, which is dead now)
    hipLaunchKernelGGL(flash_attn_kernel, dim3(32 * 16), dim3(256), 0, stream, qb, kb, vb, ob);
    // 8. wo projection + residual(h) -> h2 (aliases qb, dead after attention)
    hipLaunchKernelGGL(gemm_f32, dim3(16, 32), dim3(256), 0, stream, ob, wo, h2, h, T_, HID_, NH_ * HD_);
    // 9. rmsnorm(h2) -> xn2
    hipLaunchKernelGGL(rmsnorm_kernel, dim3(T_), dim3(256), 0, stream, h2, ln2_w, xn2);
    // 10. gating
    hipLaunchKernelGGL(gating_kernel, dim3(T_), dim3(64), 0, stream, xn2, gate_w, sel, wtb, counts);
    // 11. prefix
    hipLaunchKernelGGL(prefix_kernel, dim3(1), dim3(64), 0, stream, counts, ebase, cursor);
    // 12. scatter
    hipLaunchKernelGGL(scatter_kernel, dim3((T_ + 255) / 256), dim3(256), 0, stream, sel, wtb, cursor, tok_list, wt_list);
    // 13. moe13: h13 = silu(Xg@w1^T)*(Xg@w3^T)
    hipLaunchKernelGGL(moe_gemm13, dim3(INTER_ / 64, T_ / 64, E_), dim3(256), 0, stream,
                       xn2, w1, w3, tok_list, ebase, counts, h13);
    // 14. out = h2
    hipLaunchKernelGGL(copy4_kernel, dim3((T_ * HID_ / 4 + 255) / 256), dim3(256), 0, stream, h2, out, T_ * HID_ / 4);
    // 15. moe2: out += wt * (h13 @ w2^T)
    hipLaunchKernelGGL(moe_gemm2, dim3(HID_ / 64, T_ / 64, E_), dim3(256), 0, stream,
                       h13, w2, tok_list, wt_list, ebase, counts, out);
}

// Round 4
// 1784.649 us; speedup vs baseline: 3.0879x; 1.8097x over previous
//
#include <hip/hip_runtime.h>
#include <hip/hip_bf16.h>
#include <math.h>

#define T_    2048
#define HID_  1024
#define NH_   16
#define NKV_  4
#define HD_   64
#define E_    8
#define TOPK_ 2
#define INTER_ 3584
#define EPS_  1e-6f

typedef __attribute__((ext_vector_type(8))) short short8;
typedef __attribute__((ext_vector_type(4))) float floatx4;

__device__ inline short f2bf(float f) {
    __hip_bfloat16 b = __float2bfloat16(f);
    return *reinterpret_cast<short*>(&b);
}

__device__ inline void cvt_store16(short* dst, float4 a, float4 b, float4 c, float4 d) {
    short8 lo, hi;
    lo[0] = f2bf(a.x); lo[1] = f2bf(a.y); lo[2] = f2bf(a.z); lo[3] = f2bf(a.w);
    lo[4] = f2bf(b.x); lo[5] = f2bf(b.y); lo[6] = f2bf(b.z); lo[7] = f2bf(b.w);
    hi[0] = f2bf(c.x); hi[1] = f2bf(c.y); hi[2] = f2bf(c.z); hi[3] = f2bf(c.w);
    hi[4] = f2bf(d.x); hi[5] = f2bf(d.y); hi[6] = f2bf(d.z); hi[7] = f2bf(d.w);
    *(short8*)dst = lo;
    *(short8*)(dst + 8) = hi;
}

// ---------------- RMSNorm: one block (256 thr) per row ----------------
__global__ __launch_bounds__(256) void rmsnorm_kernel(const float* __restrict__ x,
                                                      const float* __restrict__ w,
                                                      float* __restrict__ o) {
    int t = blockIdx.x;
    const float* xr = x + (size_t)t * HID_;
    float s = 0.f;
    for (int d = threadIdx.x; d < HID_; d += 256) { float v = xr[d]; s += v * v; }
    __shared__ float red[256];
    red[threadIdx.x] = s; __syncthreads();
    for (int off = 128; off > 0; off >>= 1) {
        if (threadIdx.x < off) red[threadIdx.x] += red[threadIdx.x + off];
        __syncthreads();
    }
    float inv = rsqrtf(red[0] / (float)HID_ + EPS_);
    for (int d = threadIdx.x; d < HID_; d += 256)
        o[(size_t)t * HID_ + d] = w[d] * xr[d] * inv;
}

// ---------------- Generic fp32 GEMM: C[M,N] = A[M,K] @ B[N,K]^T (+add) ----------------
__global__ __launch_bounds__(256) void gemm_f32(const float* __restrict__ A,
                                                const float* __restrict__ B,
                                                float* __restrict__ C,
                                                const float* __restrict__ addsrc,
                                                int M, int N, int K) {
    __shared__ float As[16][65];
    __shared__ float Bs[16][65];
    int tid = threadIdx.x;
    int tx = tid & 15, ty = tid >> 4;
    int bm = blockIdx.y * 64, bn = blockIdx.x * 64;
    float acc[4][4];
#pragma unroll
    for (int i = 0; i < 4; i++)
#pragma unroll
        for (int j = 0; j < 4; j++) acc[i][j] = 0.f;

    int mL[4], kL[4];
#pragma unroll
    for (int l = 0; l < 4; l++) { int idx = tid + l * 256; mL[l] = idx >> 4; kL[l] = idx & 15; }

    for (int k0 = 0; k0 < K; k0 += 16) {
#pragma unroll
        for (int l = 0; l < 4; l++) {
            int m = mL[l], kk = kL[l];
            int gr = bm + m;
            As[kk][m] = (gr < M) ? A[(size_t)gr * K + k0 + kk] : 0.f;
            int gc = bn + m;
            Bs[kk][m] = (gc < N) ? B[(size_t)gc * K + k0 + kk] : 0.f;
        }
        __syncthreads();
#pragma unroll
        for (int kk = 0; kk < 16; kk++) {
            float a[4], b[4];
#pragma unroll
            for (int i = 0; i < 4; i++) a[i] = As[kk][ty * 4 + i];
#pragma unroll
            for (int j = 0; j < 4; j++) b[j] = Bs[kk][tx * 4 + j];
#pragma unroll
            for (int i = 0; i < 4; i++)
#pragma unroll
                for (int j = 0; j < 4; j++) acc[i][j] += a[i] * b[j];
        }
        __syncthreads();
    }
#pragma unroll
    for (int i = 0; i < 4; i++) {
        int r = bm + ty * 4 + i;
        if (r >= M) continue;
#pragma unroll
        for (int j = 0; j < 4; j++) {
            int c = bn + tx * 4 + j;
            if (c >= N) continue;
            float v = acc[i][j];
            if (addsrc) v += addsrc[(size_t)r * N + c];
            C[(size_t)r * N + c] = v;
        }
    }
}

// ---------------- RoPE in-place on q and k ----------------
__global__ void rope_kernel(float* __restrict__ qb, float* __restrict__ kb,
                            const int* __restrict__ pos_ids) {
    int idx = blockIdx.x * blockDim.x + threadIdx.x;
    const int totq = T_ * NH_ * 32;
    const int totk = T_ * NKV_ * 32;
    if (idx >= totq + totk) return;
    float* buf; int t, hh, i, hw;
    if (idx < totq) { buf = qb; hw = NH_;  t = idx / (NH_ * 32); int r = idx % (NH_ * 32); hh = r / 32; i = r % 32; }
    else { idx -= totq; buf = kb; hw = NKV_; t = idx / (NKV_ * 32); int r = idx % (NKV_ * 32); hh = r / 32; i = r % 32; }
    float pos = (float)pos_ids[t];
    float inv = expf(-(float)i * (13.815510558f / 32.0f));
    float fr = pos * inv;
    float c = cosf(fr), s = sinf(fr);
    size_t base = (size_t)t * hw * 64 + (size_t)hh * 64;
    float x1 = buf[base + i], x2 = buf[base + i + 32];
    buf[base + i]      = x1 * c - x2 * s;
    buf[base + i + 32] = x2 * c + x1 * s;
}

// ---------------- Flash attention: one block per (head, 64-row q-tile) ----------------
__global__ __launch_bounds__(256) void flash_attn_kernel(const float* __restrict__ qb,
                                                         const float* __restrict__ kb,
                                                         const float* __restrict__ vb,
                                                         float* __restrict__ ob) {
    __shared__ float Qs[64][68];
    __shared__ float Ks[64][68];
    __shared__ float Vs[64][68];
    __shared__ float Ps[64][68];

    int bid = blockIdx.x;
    int h = bid & 15;
    int qr = bid >> 4;
    int qt = (qr & 1) ? (31 - (qr >> 1)) : (qr >> 1);
    int q0 = qt * 64;
    int kvh = h >> 2;
    int tid = threadIdx.x;
    int tx = tid & 15, ty = tid >> 4;

#pragma unroll
    for (int l = 0; l < 16; l++) {
        int idx = l * 256 + tid;
        int m = idx >> 6, d = idx & 63;
        Qs[d][m] = qb[(size_t)(q0 + m) * (NH_ * HD_) + h * HD_ + d];
    }

    float o_acc[4][4];
    float m_i[4], l_i[4];
#pragma unroll
    for (int i = 0; i < 4; i++) {
        m_i[i] = -INFINITY; l_i[i] = 0.f;
#pragma unroll
        for (int j = 0; j < 4; j++) o_acc[i][j] = 0.f;
    }

    for (int t0 = 0; t0 <= q0; t0 += 64) {
        __syncthreads();
#pragma unroll
        for (int l = 0; l < 16; l++) {
            int idx = l * 256 + tid;
            int m = idx >> 6, d = idx & 63;
            size_t g = (size_t)(t0 + m) * (NKV_ * HD_) + kvh * HD_ + d;
            Ks[d][m] = kb[g];
            Vs[m][d] = vb[g];
        }
        __syncthreads();

        float s[4][4];
#pragma unroll
        for (int i = 0; i < 4; i++)
#pragma unroll
            for (int j = 0; j < 4; j++) s[i][j] = 0.f;
#pragma unroll 4
        for (int kk = 0; kk < 64; kk++) {
            float4 a4 = *(const float4*)&Qs[kk][ty * 4];
            float4 b4 = *(const float4*)&Ks[kk][tx * 4];
            float a[4] = {a4.x, a4.y, a4.z, a4.w};
            float b[4] = {b4.x, b4.y, b4.z, b4.w};
#pragma unroll
            for (int i = 0; i < 4; i++)
#pragma unroll
                for (int j = 0; j < 4; j++) s[i][j] += a[i] * b[j];
        }

        bool diag = (t0 == q0);
#pragma unroll
        for (int i = 0; i < 4; i++) {
#pragma unroll
            for (int j = 0; j < 4; j++) {
                s[i][j] *= 0.125f;
                if (diag && (t0 + tx * 4 + j > q0 + ty * 4 + i)) s[i][j] = -INFINITY;
            }
        }

#pragma unroll
        for (int i = 0; i < 4; i++) {
            float mx = fmaxf(fmaxf(s[i][0], s[i][1]), fmaxf(s[i][2], s[i][3]));
#pragma unroll
            for (int off = 8; off >= 1; off >>= 1) mx = fmaxf(mx, __shfl_xor(mx, off));
            float mn = fmaxf(m_i[i], mx);
            float alpha = __expf(m_i[i] - mn);
            float rs = 0.f;
#pragma unroll
            for (int j = 0; j < 4; j++) { float p = __expf(s[i][j] - mn); s[i][j] = p; rs += p; }
#pragma unroll
            for (int off = 8; off >= 1; off >>= 1) rs += __shfl_xor(rs, off);
            l_i[i] = l_i[i] * alpha + rs;
            m_i[i] = mn;
#pragma unroll
            for (int j = 0; j < 4; j++) o_acc[i][j] *= alpha;
        }

#pragma unroll
        for (int j = 0; j < 4; j++)
#pragma unroll
            for (int i = 0; i < 4; i++)
                Ps[tx * 4 + j][ty * 4 + i] = s[i][j];
        __syncthreads();

#pragma unroll 4
        for (int kk = 0; kk < 64; kk++) {
            float4 a4 = *(const float4*)&Ps[kk][ty * 4];
            float4 b4 = *(const float4*)&Vs[kk][tx * 4];
            float a[4] = {a4.x, a4.y, a4.z, a4.w};
            float b[4] = {b4.x, b4.y, b4.z, b4.w};
#pragma unroll
            for (int i = 0; i < 4; i++)
#pragma unroll
                for (int j = 0; j < 4; j++) o_acc[i][j] += a[i] * b[j];
        }
    }

#pragma unroll
    for (int i = 0; i < 4; i++) {
        float invl = 1.f / l_i[i];
        int r = q0 + ty * 4 + i;
#pragma unroll
        for (int j = 0; j < 4; j++)
            ob[(size_t)r * (NH_ * HD_) + h * HD_ + tx * 4 + j] = o_acc[i][j] * invl;
    }
}

// ---------------- Gating: one wave per token ----------------
__global__ __launch_bounds__(64) void gating_kernel(const float* __restrict__ xn2,
                                                    const float* __restrict__ gate_w,
                                                    int* __restrict__ sel,
                                                    float* __restrict__ wt,
                                                    int* __restrict__ counts) {
    int t = blockIdx.x, lane = threadIdx.x;
    const float* x = xn2 + (size_t)t * HID_;
    float logits[E_];
    for (int e = 0; e < E_; e++) {
        float p = 0.f;
        for (int d = lane; d < HID_; d += 64) p += x[d] * gate_w[(size_t)e * HID_ + d];
#pragma unroll
        for (int off = 32; off > 0; off >>= 1) p += __shfl_xor(p, off);
        logits[e] = p;
    }
    float mx = logits[0];
    for (int e = 1; e < E_; e++) mx = fmaxf(mx, logits[e]);
    float pr[E_]; float sum = 0.f;
    for (int e = 0; e < E_; e++) { pr[e] = __expf(logits[e] - mx); sum += pr[e]; }
    int e1 = 0; float p1 = pr[0];
    for (int e = 1; e < E_; e++) if (pr[e] > p1) { p1 = pr[e]; e1 = e; }
    int e2 = -1; float p2 = -1.f;
    for (int e = 0; e < E_; e++) if (e != e1 && pr[e] > p2) { p2 = pr[e]; e2 = e; }
    if (lane == 0) {
        float denom = p1 + p2;
        sel[t * 2] = e1; sel[t * 2 + 1] = e2;
        wt[t * 2] = p1 / denom; wt[t * 2 + 1] = p2 / denom;
        atomicAdd(&counts[e1], 1);
        atomicAdd(&counts[e2], 1);
    }
}

__global__ void init_counts_kernel(int* counts) {
    if (threadIdx.x < E_) counts[threadIdx.x] = 0;
}

__global__ void prefix_kernel(const int* __restrict__ counts, int* __restrict__ ebase,
                              int* __restrict__ cursor) {
    if (threadIdx.x == 0) {
        int b = 0;
        for (int e = 0; e < E_; e++) { ebase[e] = b; cursor[e] = b; b += counts[e]; }
    }
}

__global__ void scatter_kernel(const int* __restrict__ sel, const float* __restrict__ wt,
                               int* __restrict__ cursor, int* __restrict__ tok_list,
                               float* __restrict__ wt_list) {
    int t = blockIdx.x * blockDim.x + threadIdx.x;
    if (t >= T_) return;
    for (int j = 0; j < 2; j++) {
        int e = sel[t * 2 + j];
        float w = wt[t * 2 + j];
        int p = atomicAdd(&cursor[e], 1);
        tok_list[p] = t;
        wt_list[p] = w;
    }
}

// ---------------- MoE GEMM 1&3, bf16 MFMA ----------------
// 128x128 tile, BK=32, 4 waves of 4x4 mfma_f32_16x16x32_bf16 frags.
// Staging converts fp32 global -> bf16 LDS. LDS row = 40 bf16 (80B, 16B-aligned,
// 2-way bank alias on frag reads = free).
__global__ __launch_bounds__(256) void moe_gemm13_mfma(const float* __restrict__ X,
                                                       const float* __restrict__ w1,
                                                       const float* __restrict__ w3,
                                                       const int* __restrict__ tok_list,
                                                       const int* __restrict__ ebase,
                                                       const int* __restrict__ counts,
                                                       __hip_bfloat16* __restrict__ h13b) {
    int e = blockIdx.z;
    int cnt = counts[e];
    int bm = blockIdx.y * 128;
    if (bm >= cnt) return;
    int base = ebase[e];
    int bn = blockIdx.x * 128;

    __shared__ alignas(16) short Xa[128 * 40];
    __shared__ alignas(16) short W1s[128 * 40];
    __shared__ alignas(16) short W3s[128 * 40];

    int tid = threadIdx.x;
    int sr = tid >> 1;            // staging row 0..127
    int scb = (tid & 1) * 16;     // staging col base 0/16

    int lrA = bm + sr;
    int tok = (lrA < cnt) ? tok_list[base + lrA] : 0;
    const float* Arow  = X + (size_t)tok * HID_ + scb;
    const float* B1row = w1 + (size_t)e * INTER_ * HID_ + (size_t)(bn + sr) * HID_ + scb;
    const float* B3row = w3 + (size_t)e * INTER_ * HID_ + (size_t)(bn + sr) * HID_ + scb;
    short* XaW = Xa  + sr * 40 + scb;
    short* W1w = W1s + sr * 40 + scb;
    short* W3w = W3s + sr * 40 + scb;

    int wvid = tid >> 6, lane = tid & 63;
    int wm = (wvid >> 1) * 64, wn = (wvid & 1) * 64;
    int l15 = lane & 15, quad = lane >> 4;

    const short* XaR = Xa  + (wm + l15) * 40 + quad * 8;
    const short* W1r = W1s + (wn + l15) * 40 + quad * 8;
    const short* W3r = W3s + (wn + l15) * 40 + quad * 8;

    floatx4 acc1[4][4], acc3[4][4];
#pragma unroll
    for (int i = 0; i < 4; i++)
#pragma unroll
        for (int j = 0; j < 4; j++) { acc1[i][j] = (floatx4)0.f; acc3[i][j] = (floatx4)0.f; }

    for (int k0 = 0; k0 < HID_; k0 += 32) {
        float4 f0 = *(const float4*)(Arow + k0);
        float4 f1 = *(const float4*)(Arow + k0 + 4);
        float4 f2 = *(const float4*)(Arow + k0 + 8);
        float4 f3 = *(const float4*)(Arow + k0 + 12);
        float4 g0 = *(const float4*)(B1row + k0);
        float4 g1 = *(const float4*)(B1row + k0 + 4);
        float4 g2 = *(const float4*)(B1row + k0 + 8);
        float4 g3 = *(const float4*)(B1row + k0 + 12);
        float4 h0 = *(const float4*)(B3row + k0);
        float4 h1 = *(const float4*)(B3row + k0 + 4);
        float4 h2 = *(const float4*)(B3row + k0 + 8);
        float4 h3 = *(const float4*)(B3row + k0 + 12);
        cvt_store16(XaW, f0, f1, f2, f3);
        cvt_store16(W1w, g0, g1, g2, g3);
        cvt_store16(W3w, h0, h1, h2, h3);
        __syncthreads();

        short8 af[4], b1f[4], b3f[4];
#pragma unroll
        for (int i = 0; i < 4; i++) af[i] = *(const short8*)(XaR + i * 16 * 40);
#pragma unroll
        for (int j = 0; j < 4; j++) {
            b1f[j] = *(const short8*)(W1r + j * 16 * 40);
            b3f[j] = *(const short8*)(W3r + j * 16 * 40);
        }
#pragma unroll
        for (int i = 0; i < 4; i++)
#pragma unroll
            for (int j = 0; j < 4; j++) {
                acc1[i][j] = __builtin_amdgcn_mfma_f32_16x16x32_bf16(af[i], b1f[j], acc1[i][j], 0, 0, 0);
                acc3[i][j] = __builtin_amdgcn_mfma_f32_16x16x32_bf16(af[i], b3f[j], acc3[i][j], 0, 0, 0);
            }
        __syncthreads();
    }

    // epilogue: C layout col=lane&15, row=quad*4+reg
#pragma unroll
    for (int i = 0; i < 4; i++) {
#pragma unroll
        for (int reg = 0; reg < 4; reg++) {
            int lrow = bm + wm + i * 16 + quad * 4 + reg;
            if (lrow >= cnt) continue;
            size_t rowoff = (size_t)(base + lrow) * INTER_;
#pragma unroll
            for (int j = 0; j < 4; j++) {
                float a = acc1[i][j][reg];
                float v = (a / (1.f + __expf(-a))) * acc3[i][j][reg];
                h13b[rowoff + bn + wn + j * 16 + l15] = __float2bfloat16(v);
            }
        }
    }
}

// ---------------- MoE GEMM 2, bf16 MFMA: out[tok] += wt * (h13b @ w2^T) ----------------
__global__ __launch_bounds__(256) void moe_gemm2_mfma(const __hip_bfloat16* __restrict__ h13b,
                                                      const float* __restrict__ w2,
                                                      const int* __restrict__ tok_list,
                                                      const float* __restrict__ wt_list,
                                                      const int* __restrict__ ebase,
                                                      const int* __restrict__ counts,
                                                      float* __restrict__ out) {
    int e = blockIdx.z;
    int cnt = counts[e];
    int bm = blockIdx.y * 128;
    if (bm >= cnt) return;
    int base = ebase[e];
    int bn = blockIdx.x * 128;

    __shared__ alignas(16) short Xa[128 * 40];
    __shared__ alignas(16) short Ws[128 * 40];

    int tid = threadIdx.x;
    int sr = tid >> 1;
    int scb = (tid & 1) * 16;

    int lrA = bm + sr;
    int slot = base + ((lrA < cnt) ? lrA : 0);
    const short* Arow = (const short*)h13b + (size_t)slot * INTER_ + scb;
    const float* Brow = w2 + (size_t)e * HID_ * INTER_ + (size_t)(bn + sr) * INTER_ + scb;
    short* XaW = Xa + sr * 40 + scb;
    short* WsW = Ws + sr * 40 + scb;

    int wvid = tid >> 6, lane = tid & 63;
    int wm = (wvid >> 1) * 64, wn = (wvid & 1) * 64;
    int l15 = lane & 15, quad = lane >> 4;

    const short* XaR = Xa + (wm + l15) * 40 + quad * 8;
    const short* WsR = Ws + (wn + l15) * 40 + quad * 8;

    floatx4 acc[4][4];
#pragma unroll
    for (int i = 0; i < 4; i++)
#pragma unroll
        for (int j = 0; j < 4; j++) acc[i][j] = (floatx4)0.f;

    for (int k0 = 0; k0 < INTER_; k0 += 32) {
        short8 v0 = *(const short8*)(Arow + k0);
        short8 v1 = *(const short8*)(Arow + k0 + 8);
        float4 g0 = *(const float4*)(Brow + k0);
        float4 g1 = *(const float4*)(Brow + k0 + 4);
        float4 g2 = *(const float4*)(Brow + k0 + 8);
        float4 g3 = *(const float4*)(Brow + k0 + 12);
        *(short8*)XaW = v0;
        *(short8*)(XaW + 8) = v1;
        cvt_store16(WsW, g0, g1, g2, g3);
        __syncthreads();

        short8 af[4], bf_[4];
#pragma unroll
        for (int i = 0; i < 4; i++) af[i] = *(const short8*)(XaR + i * 16 * 40);
#pragma unroll
        for (int j = 0; j < 4; j++) bf_[j] = *(const short8*)(WsR + j * 16 * 40);
#pragma unroll
        for (int i = 0; i < 4; i++)
#pragma unroll
            for (int j = 0; j < 4; j++)
                acc[i][j] = __builtin_amdgcn_mfma_f32_16x16x32_bf16(af[i], bf_[j], acc[i][j], 0, 0, 0);
        __syncthreads();
    }

#pragma unroll
    for (int i = 0; i < 4; i++) {
#pragma unroll
        for (int reg = 0; reg < 4; reg++) {
            int lrow = bm + wm + i * 16 + quad * 4 + reg;
            if (lrow >= cnt) continue;
            int tok = tok_list[base + lrow];
            float w = wt_list[base + lrow];
            size_t rowoff = (size_t)tok * HID_;
#pragma unroll
            for (int j = 0; j < 4; j++)
                atomicAdd(&out[rowoff + bn + wn + j * 16 + l15], w * acc[i][j][reg]);
        }
    }
}

__global__ void copy4_kernel(const float* __restrict__ src, float* __restrict__ dst, int n4) {
    int i = blockIdx.x * blockDim.x + threadIdx.x;
    if (i < n4) ((float4*)dst)[i] = ((const float4*)src)[i];
}

extern "C" void kernel_launch(void* const* d_in, const int* in_sizes, int n_in,
                              void* d_out, int out_size, void* d_ws, size_t ws_size,
                              hipStream_t stream) {
    const float* h      = (const float*)d_in[0];
    const int*   pos    = (const int*)d_in[1];
    const float* wq     = (const float*)d_in[2];
    const float* wk     = (const float*)d_in[3];
    const float* wv     = (const float*)d_in[4];
    const float* wo     = (const float*)d_in[5];
    const float* gate_w = (const float*)d_in[6];
    const float* w1     = (const float*)d_in[7];
    const float* w2     = (const float*)d_in[8];
    const float* w3     = (const float*)d_in[9];
    const float* ln1_w  = (const float*)d_in[10];
    const float* ln2_w  = (const float*)d_in[11];
    float* out = (float*)d_out;

    float* ws = (float*)d_ws;
    const size_t M1 = 1024 * 1024;
    float* xn1 = ws;                 // 2M floats (alias: ob)
    float* ob  = ws;
    float* qb  = ws + 2 * M1;        // 2M (alias: h2)
    float* h2  = ws + 2 * M1;
    float* kb  = ws + 4 * M1;        // 0.5M
    float* vb  = ws + 4 * M1 + M1 / 2; // 0.5M
    float* xn2 = ws + 5 * M1;        // 2M
    __hip_bfloat16* h13b = (__hip_bfloat16*)(ws + 7 * M1);  // 4096*3584 bf16 = 7.17M floats eq
    float* smallf = ws + 14 * M1 + M1 / 2;
    int*   sel      = (int*)smallf;
    float* wtb      = smallf + 4096;
    int*   counts   = (int*)(smallf + 8192);
    int*   ebase    = (int*)(smallf + 8192 + 16);
    int*   cursor   = (int*)(smallf + 8192 + 32);
    int*   tok_list = (int*)(smallf + 8192 + 64);
    float* wt_list  = smallf + 8192 + 64 + 4352;

    hipLaunchKernelGGL(init_counts_kernel, dim3(1), dim3(64), 0, stream, counts);
    hipLaunchKernelGGL(rmsnorm_kernel, dim3(T_), dim3(256), 0, stream, h, ln1_w, xn1);
    hipLaunchKernelGGL(gemm_f32, dim3(16, 32), dim3(256), 0, stream, xn1, wq, qb, (const float*)nullptr, T_, NH_ * HD_, HID_);
    hipLaunchKernelGGL(gemm_f32, dim3(4, 32),  dim3(256), 0, stream, xn1, wk, kb, (const float*)nullptr, T_, NKV_ * HD_, HID_);
    hipLaunchKernelGGL(gemm_f32, dim3(4, 32),  dim3(256), 0, stream, xn1, wv, vb, (const float*)nullptr, T_, NKV_ * HD_, HID_);
    {
        int tot = T_ * (NH_ + NKV_) * 32;
        hipLaunchKernelGGL(rope_kernel, dim3((tot + 255) / 256), dim3(256), 0, stream, qb, kb, pos);
    }
    hipLaunchKernelGGL(flash_attn_kernel, dim3(32 * 16), dim3(256), 0, stream, qb, kb, vb, ob);
    hipLaunchKernelGGL(gemm_f32, dim3(16, 32), dim3(256), 0, stream, ob, wo, h2, h, T_, HID_, NH_ * HD_);
    hipLaunchKernelGGL(rmsnorm_kernel, dim3(T_), dim3(256), 0, stream, h2, ln2_w, xn2);
    hipLaunchKernelGGL(gating_kernel, dim3(T_), dim3(64), 0, stream, xn2, gate_w, sel, wtb, counts);
    hipLaunchKernelGGL(prefix_kernel, dim3(1), dim3(64), 0, stream, counts, ebase, cursor);
    hipLaunchKernelGGL(scatter_kernel, dim3((T_ + 255) / 256), dim3(256), 0, stream, sel, wtb, cursor, tok_list, wt_list);
    // moe13: h13b = silu(Xg@w1^T)*(Xg@w3^T), bf16 MFMA
    hipLaunchKernelGGL(moe_gemm13_mfma, dim3(INTER_ / 128, 16, E_), dim3(256), 0, stream,
                       xn2, w1, w3, tok_list, ebase, counts, h13b);
    // out = h2
    hipLaunchKernelGGL(copy4_kernel, dim3((T_ * HID_ / 4 + 255) / 256), dim3(256), 0, stream, h2, out, T_ * HID_ / 4);
    // moe2: out += wt * (h13b @ w2^T), bf16 MFMA
    hipLaunchKernelGGL(moe_gemm2_mfma, dim3(HID_ / 128, 16, E_), dim3(256), 0, stream,
                       h13b, w2, tok_list, wt_list, ebase, counts, out);
}